// Round 6
// baseline (944.359 us; speedup 1.0000x reference)
//
#include <hip/hip_runtime.h>

typedef unsigned short u16;
typedef unsigned int   u32;
typedef unsigned long long u64;
typedef __attribute__((ext_vector_type(8))) __bf16 bf16x8;
typedef __attribute__((ext_vector_type(4))) float  f32x4;

#define B_   32
#define T_   64
#define S_   128
#define E_   256
#define H_   512
#define ENC_ 512
#define V_   32000

__device__ __forceinline__ float b2f(u16 u) {
  union { u32 i; float f; } v; v.i = ((u32)u) << 16; return v.f;
}
__device__ __forceinline__ u16 f2b(float f) {
  union { float f; u32 i; } v; v.f = f;
  u32 r = (v.i + 0x7fffu + ((v.i >> 16) & 1u)) >> 16;
  return (u16)r;
}
__device__ __forceinline__ float sigm(float x) { return 1.f / (1.f + __expf(-x)); }

// async global->LDS, 16B per lane. LDS dest must be wave-uniform base + lane*16.
__device__ __forceinline__ void async_ld16(const void* g, void* l) {
  __builtin_amdgcn_global_load_lds((const __attribute__((address_space(1))) u32*)g,
                                   (__attribute__((address_space(3))) u32*)l,
                                   16, 0, 0);
}

// ---------------------------------------------------------------------------
// f32 -> bf16 convert, 4 elems/thread (float4 in, 8B out). n % 4 == 0.
// ---------------------------------------------------------------------------
__global__ __launch_bounds__(256) void k_cvt(const float* __restrict__ src,
                                             u16* __restrict__ dst, int n4) {
  int i = blockIdx.x * 256 + threadIdx.x;
  if (i < n4) {
    float4 v = ((const float4*)src)[i];
    ushort4 o;
    o.x = f2b(v.x); o.y = f2b(v.y); o.z = f2b(v.z); o.w = f2b(v.w);
    ((ushort4*)dst)[i] = o;
  }
}

// ---------------------------------------------------------------------------
// Generic bf16 B^T GEMM (m97-style): C[M,N] = A[M,K] * B[N,K]^T (+bias1+bias2)
// 128x128 tile, BK=64, 4 waves (2x2 of 64x64), 16x16x32 bf16 MFMA.
// XCD-chunked tile swizzle (bijective when nwg%8==0).
// ---------------------------------------------------------------------------
template <typename OUT_T>
__global__ __launch_bounds__(256) void gemm_bt(
    const u16* __restrict__ A, int lda,
    const u16* __restrict__ B, int ldb,
    OUT_T* __restrict__ C, int ldc, int K,
    const float* __restrict__ bias1, const float* __restrict__ bias2) {
  __shared__ __align__(16) u16 As[128 * 64];
  __shared__ __align__(16) u16 Bs[128 * 64];

  const int tid  = threadIdx.x;
  int f = blockIdx.y * gridDim.x + blockIdx.x;
  const int nwg = gridDim.x * gridDim.y;
  int g = (nwg & 7) ? f : ((f & 7) * (nwg >> 3) + (f >> 3));
  const int m0 = (g % gridDim.x) * 128;
  const int n0 = (g / gridDim.x) * 128;
  const int wave = tid >> 6, lane = tid & 63;
  const int mw = (wave >> 1) * 64, nw = (wave & 1) * 64;
  const int lr = lane & 15, lq = lane >> 4;

  f32x4 acc[4][4];
#pragma unroll
  for (int i = 0; i < 4; ++i)
#pragma unroll
    for (int j = 0; j < 4; ++j) acc[i][j] = (f32x4){0.f, 0.f, 0.f, 0.f};

  for (int k0 = 0; k0 < K; k0 += 64) {
#pragma unroll
    for (int it = 0; it < 4; ++it) {
      int chunk = it * 256 + tid;       // 0..1023 16B-chunks
      int row = chunk >> 3;
      int kc  = (chunk & 7) << 3;
      async_ld16(&A[(size_t)(m0 + row) * lda + k0 + kc], &As[chunk << 3]);
    }
#pragma unroll
    for (int it = 0; it < 4; ++it) {
      int chunk = it * 256 + tid;
      int row = chunk >> 3;
      int kc  = (chunk & 7) << 3;
      async_ld16(&B[(size_t)(n0 + row) * ldb + k0 + kc], &Bs[chunk << 3]);
    }
    __syncthreads();  // drains vmcnt (global_load_lds) + barrier
#pragma unroll
    for (int kk = 0; kk < 2; ++kk) {
      bf16x8 af[4], bf[4];
#pragma unroll
      for (int i = 0; i < 4; ++i)
        af[i] = *(const bf16x8*)&As[(mw + i * 16 + lr) * 64 + kk * 32 + lq * 8];
#pragma unroll
      for (int j = 0; j < 4; ++j)
        bf[j] = *(const bf16x8*)&Bs[(nw + j * 16 + lr) * 64 + kk * 32 + lq * 8];
#pragma unroll
      for (int i = 0; i < 4; ++i)
#pragma unroll
        for (int j = 0; j < 4; ++j)
          acc[i][j] = __builtin_amdgcn_mfma_f32_16x16x32_bf16(af[i], bf[j], acc[i][j], 0, 0, 0);
    }
    __syncthreads();
  }

#pragma unroll
  for (int j = 0; j < 4; ++j) {
    int n = n0 + nw + j * 16 + lr;
    float bs = 0.f;
    if (bias1) bs += bias1[n];
    if (bias2) bs += bias2[n];
#pragma unroll
    for (int i = 0; i < 4; ++i) {
#pragma unroll
      for (int r = 0; r < 4; ++r) {
        int m = m0 + mw + i * 16 + lq * 4 + r;
        float v = acc[i][j][r] + bs;
        if constexpr (sizeof(OUT_T) == 2)
          C[(size_t)m * ldc + n] = (OUT_T)f2b(v);
        else
          C[(size_t)m * ldc + n] = v;
      }
    }
  }
}

// ---------------------------------------------------------------------------
// 64x64-tile variant for skinny GEMMs (q, ho): 4x the block count of the
// 128-tile kernel on M=2048/N=512 shapes -> 256 blocks hide the per-iter
// stage latency across 4x more CUs. Same wave layout, 2x2 fragments.
// ---------------------------------------------------------------------------
template <typename OUT_T>
__global__ __launch_bounds__(256) void gemm64(
    const u16* __restrict__ A, int lda,
    const u16* __restrict__ B, int ldb,
    OUT_T* __restrict__ C, int ldc, int K,
    const float* __restrict__ bias1, const float* __restrict__ bias2) {
  __shared__ __align__(16) u16 As[64 * 64];
  __shared__ __align__(16) u16 Bs[64 * 64];

  const int tid  = threadIdx.x;
  int f = blockIdx.y * gridDim.x + blockIdx.x;
  const int nwg = gridDim.x * gridDim.y;
  int g = (nwg & 7) ? f : ((f & 7) * (nwg >> 3) + (f >> 3));
  const int m0 = (g % gridDim.x) * 64;
  const int n0 = (g / gridDim.x) * 64;
  const int wave = tid >> 6, lane = tid & 63;
  const int mw = (wave >> 1) * 32, nw = (wave & 1) * 32;
  const int lr = lane & 15, lq = lane >> 4;

  f32x4 acc[2][2];
#pragma unroll
  for (int i = 0; i < 2; ++i)
#pragma unroll
    for (int j = 0; j < 2; ++j) acc[i][j] = (f32x4){0.f, 0.f, 0.f, 0.f};

  for (int k0 = 0; k0 < K; k0 += 64) {
#pragma unroll
    for (int it = 0; it < 2; ++it) {
      int chunk = it * 256 + tid;       // 0..511 16B-chunks
      int row = chunk >> 3;
      int kc  = (chunk & 7) << 3;
      async_ld16(&A[(size_t)(m0 + row) * lda + k0 + kc], &As[chunk << 3]);
    }
#pragma unroll
    for (int it = 0; it < 2; ++it) {
      int chunk = it * 256 + tid;
      int row = chunk >> 3;
      int kc  = (chunk & 7) << 3;
      async_ld16(&B[(size_t)(n0 + row) * ldb + k0 + kc], &Bs[chunk << 3]);
    }
    __syncthreads();
#pragma unroll
    for (int kk = 0; kk < 2; ++kk) {
      bf16x8 af[2], bf[2];
#pragma unroll
      for (int i = 0; i < 2; ++i)
        af[i] = *(const bf16x8*)&As[(mw + i * 16 + lr) * 64 + kk * 32 + lq * 8];
#pragma unroll
      for (int j = 0; j < 2; ++j)
        bf[j] = *(const bf16x8*)&Bs[(nw + j * 16 + lr) * 64 + kk * 32 + lq * 8];
#pragma unroll
      for (int i = 0; i < 2; ++i)
#pragma unroll
        for (int j = 0; j < 2; ++j)
          acc[i][j] = __builtin_amdgcn_mfma_f32_16x16x32_bf16(af[i], bf[j], acc[i][j], 0, 0, 0);
    }
    __syncthreads();
  }

#pragma unroll
  for (int j = 0; j < 2; ++j) {
    int n = n0 + nw + j * 16 + lr;
    float bs = 0.f;
    if (bias1) bs += bias1[n];
    if (bias2) bs += bias2[n];
#pragma unroll
    for (int i = 0; i < 2; ++i) {
#pragma unroll
      for (int r = 0; r < 4; ++r) {
        int m = m0 + mw + i * 16 + lq * 4 + r;
        float v = acc[i][j][r] + bs;
        if constexpr (sizeof(OUT_T) == 2)
          C[(size_t)m * ldc + n] = (OUT_T)f2b(v);
        else
          C[(size_t)m * ldc + n] = v;
      }
    }
  }
}

// ---------------------------------------------------------------------------
// Embedding gather + f32->bf16: emb[bt][e] = bf16(table[tok[bt]][e]).
// ---------------------------------------------------------------------------
__global__ __launch_bounds__(256) void k_embed(const int* __restrict__ toks,
                                               const float* __restrict__ table,
                                               u16* __restrict__ emb) {
  int id  = blockIdx.x * 256 + threadIdx.x;
  int row = id >> 6;
  int c4  = (id & 63) << 2;
  int tok = toks[row];
  float4 v = *(const float4*)&table[(size_t)tok * E_ + c4];
  ushort4 o;
  o.x = f2b(v.x); o.y = f2b(v.y); o.z = f2b(v.z); o.w = f2b(v.w);
  *(ushort4*)&emb[(size_t)row * E_ + c4] = o;
}

// ---------------------------------------------------------------------------
// Wa transpose + convert: WaT[e][h] = bf16(Wa[h][e])  (512x512).
// ---------------------------------------------------------------------------
__global__ __launch_bounds__(256) void k_transpose(const float* __restrict__ Wa,
                                                   u16* __restrict__ WaT) {
  __shared__ float tle[32][33];
  int bx = blockIdx.x * 32;  // h
  int by = blockIdx.y * 32;  // e
  int tid = threadIdx.x;
  for (int i = tid; i < 1024; i += 256) {
    int r = i >> 5, c = i & 31;
    tle[r][c] = Wa[(size_t)(bx + r) * ENC_ + by + c];
  }
  __syncthreads();
  for (int i = tid; i < 1024; i += 256) {
    int r = i >> 5, c = i & 31;
    WaT[(size_t)(by + r) * H_ + bx + c] = f2b(tle[c][r]);
  }
}

// ---------------------------------------------------------------------------
// Sequential LSTM core. 64 persistent blocks. Block n owns h-indices
// [8n,8n+8) => W_hh rows {g*512+8n+j} held in regs.
//
// Round 6: REGISTER-DIRECT sentinel exchange, compiler-safe coherence.
// Each lane's MFMA A-fragment is 16 x 16B chunks of h_{t-1} (row am,
// bytes lq*16 + ks*64). The poll loads those chunks straight into
// registers via __hip_atomic_load u64 (RELAXED, AGENT) -- the compiler
// emits the correct gfx950 cache-bypass flags (the hand-written sc1 asm
// of round 5 risked a stale-L1 livelock). Sentinel 0xFFFF..F (bf16 NaN
// pair, impossible from f2b(sigm*tanh)) is re-loaded until cleared.
// No LDS staging for A at all: no Hs buffer, no restage barrier, no
// ds_read bank conflicts. s_sleep before the poll skips the guaranteed
// first-miss round; s_sleep(2) backoff in the retry reduces MALL
// congestion. Hbuf slot 0 = bf16(h0); slot t+1 = h_t; slots 1..64
// pre-poisoned 0xFF.
// ---------------------------------------------------------------------------
__global__ __launch_bounds__(256) void k_lstm(
    const u16* __restrict__ Whh,   // bf16 [2048][512]
    const float* __restrict__ gp,  // gates_pre [B*T][2048]
    const float* __restrict__ c0,  // [32][512] f32
    u16* __restrict__ Hbuf,        // [65][32][512] bf16; slots 1..64 poisoned
    u16* __restrict__ hc) {        // [B*T][1024] bf16, cols 0..511 = h
  const int blk  = blockIdx.x;
  const int tid  = threadIdx.x;
  const int wave = tid >> 6, lane = tid & 63;
  const int mi = wave >> 1, ni = wave & 1;
  const int lr = lane & 15, lq = lane >> 4;

  // B-operand (W_hh rows) resident in registers for whole kernel.
  const int p    = ni * 16 + lr;                          // col within 32-set
  const int grow = (p >> 3) * H_ + blk * 8 + (p & 7);     // global gate row
  bf16x8 bfr[16];
#pragma unroll
  for (int ks = 0; ks < 16; ++ks)
    bfr[ks] = *(const bf16x8*)&Whh[(size_t)grow * H_ + ks * 32 + lq * 8];

  // c-state: thread (b=tid>>3, j=tid&7) owns c[b][blk*8+j] in a register.
  const int pb = tid >> 3, pj = tid & 7;
  const int hidx = blk * 8 + pj;
  float c = c0[pb * H_ + hidx];

  __shared__ float G[32][33];  // +1 pad

  const int am = mi * 16 + lr;  // this lane's A-row (batch)

  // A-fragments in registers as 32 u64 (16 x 16B chunks).
  u64 af8[32];
  {
    const u64* a0p = (const u64*)((const char*)Hbuf + (size_t)am * 1024 + lq * 16);
#pragma unroll
    for (int ks = 0; ks < 16; ++ks) {
      af8[2 * ks]     = a0p[ks * 8];      // slot 0: plain cached loads
      af8[2 * ks + 1] = a0p[ks * 8 + 1];
    }
  }

  // prefetch gp for t=0
  float gpr[4];
#pragma unroll
  for (int r = 0; r < 4; ++r)
    gpr[r] = gp[(size_t)((mi * 16 + lq * 4 + r) * T_ + 0) * 2048 + grow];

  for (int t = 0; t < T_; ++t) {
    f32x4 acc = (f32x4){0.f, 0.f, 0.f, 0.f};
#pragma unroll
    for (int ks = 0; ks < 16; ++ks) {
      union { u64 q[2]; bf16x8 v; } uu;
      uu.q[0] = af8[2 * ks]; uu.q[1] = af8[2 * ks + 1];
      acc = __builtin_amdgcn_mfma_f32_16x16x32_bf16(uu.v, bfr[ks], acc, 0, 0, 0);
    }
    __syncthreads();  // all G reads of step t-1 complete before overwrite
#pragma unroll
    for (int r = 0; r < 4; ++r)
      G[mi * 16 + lq * 4 + r][p] = acc[r] + gpr[r];
    __syncthreads();  // G of step t visible

    if (t < T_ - 1) {
      // issue next step's gp now: HBM latency overlaps pointwise+exchange
#pragma unroll
      for (int r = 0; r < 4; ++r)
        gpr[r] = gp[(size_t)((mi * 16 + lq * 4 + r) * T_ + t + 1) * 2048 + grow];
    }

    // pointwise: i,f,g,o at cols j, 8+j, 16+j, 24+j of the 32-set
    float gi = G[pb][pj], gf = G[pb][8 + pj], gg = G[pb][16 + pj], go = G[pb][24 + pj];
    c = sigm(gf) * c + sigm(gi) * tanhf(gg);
    float h = sigm(go) * tanhf(c);
    u16 hb = f2b(h);
    // pack neighbor's h (pj^1, same wave) and publish as one u32.
    u32 other = (u32)__shfl_xor((int)(u32)hb, 1);
    if (!(tid & 1)) {
      u32 pk = (u32)hb | (other << 16);
      __hip_atomic_store((u32*)&Hbuf[(size_t)(t + 1) * (B_ * H_) + pb * H_ + hidx], pk,
                         __ATOMIC_RELAXED, __HIP_MEMORY_SCOPE_AGENT);
      *(u32*)&hc[(size_t)(pb * T_ + t) * 1024 + hidx] = pk;
    }

    if (t < T_ - 1) {
      __builtin_amdgcn_s_sleep(12);  // ~0.3us: let peer stores land first
      const u64* hsrc = (const u64*)((const char*)Hbuf +
          ((size_t)(t + 1) * (B_ * H_) + (size_t)am * H_) * 2 + lq * 16);
#pragma unroll
      for (int ks = 0; ks < 16; ++ks) {
        af8[2 * ks] = __hip_atomic_load(&hsrc[ks * 8], __ATOMIC_RELAXED,
                                        __HIP_MEMORY_SCOPE_AGENT);
        af8[2 * ks + 1] = __hip_atomic_load(&hsrc[ks * 8 + 1], __ATOMIC_RELAXED,
                                            __HIP_MEMORY_SCOPE_AGENT);
      }
      for (;;) {
        u32 bad = 0;
#pragma unroll
        for (int i = 0; i < 32; ++i) bad |= (af8[i] == ~0ull);
        if (!bad) break;
        __builtin_amdgcn_s_sleep(2);
#pragma unroll
        for (int i = 0; i < 32; ++i)
          if (af8[i] == ~0ull)
            af8[i] = __hip_atomic_load(&hsrc[(i >> 1) * 8 + (i & 1)],
                                       __ATOMIC_RELAXED, __HIP_MEMORY_SCOPE_AGENT);
      }
    }
  }
}

// ---------------------------------------------------------------------------
// Attention: one block per (b,t). scores = q . enc, mask, softmax, ctx.
// enc here is the bf16 copy. Writes ctx (bf16) into hc cols 512..1023.
// ---------------------------------------------------------------------------
__global__ __launch_bounds__(256) void k_attn(
    const u16* __restrict__ q,    // bf16 [B*T][512]
    const u16* __restrict__ enc,  // bf16 [B][S][512]
    const int* __restrict__ lens, // [B]
    u16* __restrict__ hc) {       // bf16 [B*T][1024]
  const int bt = blockIdx.x;
  const int b  = bt >> 6;  // bt = b*T + t
  const int tid = threadIdx.x;
  const int len = lens[b];

  __shared__ float qs[512];
  __shared__ float sc[128];
  __shared__ float red2[256];
  __shared__ float sred[2];

  for (int i = tid; i < 512; i += 256) qs[i] = b2f(q[(size_t)bt * 512 + i]);
  __syncthreads();

  // scores: thread (s = tid&127, half = tid>>7) sums 256 of 512 k's
  {
    int s = tid & 127, half = tid >> 7;
    const u16* er = &enc[((size_t)b * S_ + s) * 512 + half * 256];
    const float* qb = &qs[half * 256];
    float a = 0.f;
#pragma unroll 4
    for (int k = 0; k < 256; k += 8) {
      uint4 raw = *(const uint4*)&er[k];
      u32 w0 = raw.x, w1 = raw.y, w2 = raw.z, w3 = raw.w;
      union { u32 i; float f; } lo, hi;
      lo.i = w0 << 16;          a += lo.f * qb[k + 0];
      hi.i = w0 & 0xffff0000u;  a += hi.f * qb[k + 1];
      lo.i = w1 << 16;          a += lo.f * qb[k + 2];
      hi.i = w1 & 0xffff0000u;  a += hi.f * qb[k + 3];
      lo.i = w2 << 16;          a += lo.f * qb[k + 4];
      hi.i = w2 & 0xffff0000u;  a += hi.f * qb[k + 5];
      lo.i = w3 << 16;          a += lo.f * qb[k + 6];
      hi.i = w3 & 0xffff0000u;  a += hi.f * qb[k + 7];
    }
    red2[tid] = a;
  }
  __syncthreads();
  if (tid < 128) {
    float v = red2[tid] + red2[tid + 128];
    sc[tid] = (tid < len) ? v : -1e30f;
  }
  __syncthreads();
  if (tid < 64) {
    float m = fmaxf(sc[tid], sc[tid + 64]);
#pragma unroll
    for (int o = 32; o > 0; o >>= 1) m = fmaxf(m, __shfl_down(m, o));
    if (tid == 0) sred[0] = m;
  }
  __syncthreads();
  float mx = sred[0];
  if (tid < 128) sc[tid] = __expf(sc[tid] - mx);
  __syncthreads();
  if (tid < 64) {
    float s2 = sc[tid] + sc[tid + 64];
#pragma unroll
    for (int o = 32; o > 0; o >>= 1) s2 += __shfl_down(s2, o);
    if (tid == 0) sred[1] = s2;
  }
  __syncthreads();
  float inv = 1.0f / sred[1];

  // ctx[e] = sum_s att[s] * enc[b][s][e]; thread handles e = tid, tid+256
  float a0 = 0.f, a1 = 0.f;
  for (int s = 0; s < S_; ++s) {
    float at = sc[s];
    const u16* er = &enc[((size_t)b * S_ + s) * 512];
    a0 += at * b2f(er[tid]);
    a1 += at * b2f(er[tid + 256]);
  }
  hc[(size_t)bt * 1024 + 512 + tid]       = f2b(a0 * inv);
  hc[(size_t)bt * 1024 + 512 + tid + 256] = f2b(a1 * inv);
}

// ---------------------------------------------------------------------------
extern "C" void kernel_launch(void* const* d_in, const int* in_sizes, int n_in,
                              void* d_out, int out_size, void* d_ws, size_t ws_size,
                              hipStream_t stream) {
  const int*   toks  = (const int*)d_in[0];
  const float* enc   = (const float*)d_in[1];
  const int*   lens  = (const int*)d_in[2];
  const float* h0    = (const float*)d_in[3];
  const float* c0    = (const float*)d_in[4];
  const float* table = (const float*)d_in[5];
  const float* W_ih  = (const float*)d_in[6];
  const float* W_hh  = (const float*)d_in[7];
  const float* b_ih  = (const float*)d_in[8];
  const float* b_hh  = (const float*)d_in[9];
  const float* Wa    = (const float*)d_in[10];
  const float* Wc_w  = (const float*)d_in[11];
  const float* Wc_b  = (const float*)d_in[12];
  const float* Wo_w  = (const float*)d_in[13];
  const float* Wo_b  = (const float*)d_in[14];
  float* out = (float*)d_out;

  char* ws = (char*)d_ws;
  size_t off = 0;
  auto alloc = [&](size_t bytes) {
    void* pp = ws + off;
    off += (bytes + 255) & ~(size_t)255;
    return pp;
  };
  float* gp    = (float*)alloc((size_t)B_ * T_ * 2048 * 4);    // 16.8 MB
  u16*   emb   = (u16*)alloc((size_t)B_ * T_ * E_ * 2);        // 1 MB
  u16*   Hbuf  = (u16*)alloc((size_t)(T_ + 1) * B_ * H_ * 2);  // 2.1 MB
  u16*   hc    = (u16*)alloc((size_t)B_ * T_ * 1024 * 2);      // 4 MB
  u16*   q     = (u16*)alloc((size_t)B_ * T_ * ENC_ * 2);      // 2 MB
  u16*   WaT   = (u16*)alloc((size_t)ENC_ * H_ * 2);           // 0.5 MB
  u16*   ho    = (u16*)alloc((size_t)B_ * T_ * H_ * 2);        // 2 MB
  u16*   Wihb  = (u16*)alloc((size_t)2048 * E_ * 2);           // 1 MB
  u16*   Whhb  = (u16*)alloc((size_t)2048 * H_ * 2);           // 2 MB
  u16*   Wcwb  = (u16*)alloc((size_t)H_ * 1024 * 2);           // 1 MB
  u16*   Wowb  = (u16*)alloc((size_t)V_ * H_ * 2);             // 32.8 MB
  u16*   encb  = (u16*)alloc((size_t)B_ * S_ * ENC_ * 2);      // 4.2 MB
  (void)in_sizes; (void)n_in; (void)out_size; (void)ws_size;

  // poison Hbuf slots 1..64 with the sentinel (0xFF bytes -> 0xFFFFFFFF words)
  hipMemsetAsync(Hbuf + (size_t)B_ * H_, 0xFF, (size_t)T_ * B_ * H_ * 2, stream);

  // 0. dtype converts (f32 -> bf16)
  k_cvt<<<(2048 * E_ / 4 + 255) / 256, 256, 0, stream>>>(W_ih, Wihb, 2048 * E_ / 4);
  k_cvt<<<(2048 * H_ / 4 + 255) / 256, 256, 0, stream>>>(W_hh, Whhb, 2048 * H_ / 4);
  k_cvt<<<(H_ * 1024 / 4 + 255) / 256, 256, 0, stream>>>(Wc_w, Wcwb, H_ * 1024 / 4);
  k_cvt<<<(V_ * H_ / 4 + 255) / 256, 256, 0, stream>>>(Wo_w, Wowb, V_ * H_ / 4);
  k_cvt<<<(B_ * S_ * ENC_ / 4 + 255) / 256, 256, 0, stream>>>(enc, encb, B_ * S_ * ENC_ / 4);
  k_cvt<<<(B_ * H_ / 4 + 255) / 256, 256, 0, stream>>>(h0, Hbuf, B_ * H_ / 4);  // slot 0
  // 1. embedding gather (+convert)
  k_embed<<<512, 256, 0, stream>>>(toks, table, emb);
  // 2. gates_pre = emb @ W_ih^T + b_ih + b_hh   [2048 x 2048], K=256, f32 out
  gemm_bt<float><<<dim3(16, 16), 256, 0, stream>>>(emb, E_, Wihb, E_, gp, 2048, E_, b_ih, b_hh);
  // 3. WaT = Wa^T (bf16)
  k_transpose<<<dim3(16, 16), 256, 0, stream>>>(Wa, WaT);
  // 4. sequential LSTM core -> h into hc[:, 0:512] and Hbuf slots 1..64
  k_lstm<<<64, 256, 0, stream>>>(Whhb, gp, c0, Hbuf, hc);
  // 5. q = h @ Wa  == hc[:,0:512] @ WaT^T   [2048 x 512], K=512, bf16 out
  gemm64<u16><<<dim3(32, 8), 256, 0, stream>>>(hc, 1024, WaT, H_, q, ENC_, H_, nullptr, nullptr);
  // 6. attention -> ctx into hc[:, 512:1024]
  k_attn<<<B_ * T_, 256, 0, stream>>>(q, encb, lens, hc);
  // 7. ho = [h,ctx] @ Wc_w^T + Wc_b   [2048 x 512], K=1024
  gemm64<u16><<<dim3(32, 8), 256, 0, stream>>>(hc, 1024, Wcwb, 1024, ho, H_, 1024, Wc_b, nullptr);
  // 8. logits = ho @ Wo^T + Wo_b -> d_out (f32)   [2048 x 32000], K=512
  gemm_bt<float><<<dim3(16, 250), 256, 0, stream>>>(ho, H_, Wowb, H_, out, V_, H_, Wo_b, nullptr);
}

// Round 7
// 828.073 us; speedup vs baseline: 1.1404x; 1.1404x over previous
//
#include <hip/hip_runtime.h>

typedef unsigned short u16;
typedef unsigned int   u32;
typedef unsigned long long u64;
typedef __attribute__((ext_vector_type(8))) __bf16 bf16x8;
typedef __attribute__((ext_vector_type(4))) float  f32x4;

#define B_   32
#define T_   64
#define S_   128
#define E_   256
#define H_   512
#define ENC_ 512
#define V_   32000

__device__ __forceinline__ float b2f(u16 u) {
  union { u32 i; float f; } v; v.i = ((u32)u) << 16; return v.f;
}
__device__ __forceinline__ u16 f2b(float f) {
  union { float f; u32 i; } v; v.f = f;
  u32 r = (v.i + 0x7fffu + ((v.i >> 16) & 1u)) >> 16;
  return (u16)r;
}
__device__ __forceinline__ float sigm(float x) { return 1.f / (1.f + __expf(-x)); }

// async global->LDS, 16B per lane. LDS dest must be wave-uniform base + lane*16.
__device__ __forceinline__ void async_ld16(const void* g, void* l) {
  __builtin_amdgcn_global_load_lds((const __attribute__((address_space(1))) u32*)g,
                                   (__attribute__((address_space(3))) u32*)l,
                                   16, 0, 0);
}

// ---------------------------------------------------------------------------
// Merged f32 -> bf16 convert for all weight/activation buffers (one launch
// instead of six). Segments resolved by cumulative-end compare; per-block
// uniform except at boundaries.
// ---------------------------------------------------------------------------
struct CvtJobs {
  const float* src[6];
  u16*         dst[6];
  int          end[6];  // cumulative n4 ends
};

__global__ __launch_bounds__(256) void k_cvt_all(CvtJobs j) {
  int i = blockIdx.x * 256 + threadIdx.x;
  if (i >= j.end[5]) return;
  const float* s; u16* d; int local;
  if      (i < j.end[0]) { s = j.src[0]; d = j.dst[0]; local = i; }
  else if (i < j.end[1]) { s = j.src[1]; d = j.dst[1]; local = i - j.end[0]; }
  else if (i < j.end[2]) { s = j.src[2]; d = j.dst[2]; local = i - j.end[1]; }
  else if (i < j.end[3]) { s = j.src[3]; d = j.dst[3]; local = i - j.end[2]; }
  else if (i < j.end[4]) { s = j.src[4]; d = j.dst[4]; local = i - j.end[3]; }
  else                   { s = j.src[5]; d = j.dst[5]; local = i - j.end[4]; }
  float4 v = ((const float4*)s)[local];
  ushort4 o;
  o.x = f2b(v.x); o.y = f2b(v.y); o.z = f2b(v.z); o.w = f2b(v.w);
  ((ushort4*)d)[local] = o;
}

// ---------------------------------------------------------------------------
// Generic bf16 B^T GEMM (m97-style): C[M,N] = A[M,K] * B[N,K]^T (+bias1+bias2)
// 128x128 tile, BK=64, 4 waves (2x2 of 64x64), 16x16x32 bf16 MFMA.
// XCD-chunked tile swizzle (bijective when nwg%8==0).
// ---------------------------------------------------------------------------
template <typename OUT_T>
__global__ __launch_bounds__(256) void gemm_bt(
    const u16* __restrict__ A, int lda,
    const u16* __restrict__ B, int ldb,
    OUT_T* __restrict__ C, int ldc, int K,
    const float* __restrict__ bias1, const float* __restrict__ bias2) {
  __shared__ __align__(16) u16 As[128 * 64];
  __shared__ __align__(16) u16 Bs[128 * 64];

  const int tid  = threadIdx.x;
  int f = blockIdx.y * gridDim.x + blockIdx.x;
  const int nwg = gridDim.x * gridDim.y;
  int g = (nwg & 7) ? f : ((f & 7) * (nwg >> 3) + (f >> 3));
  const int m0 = (g % gridDim.x) * 128;
  const int n0 = (g / gridDim.x) * 128;
  const int wave = tid >> 6, lane = tid & 63;
  const int mw = (wave >> 1) * 64, nw = (wave & 1) * 64;
  const int lr = lane & 15, lq = lane >> 4;

  f32x4 acc[4][4];
#pragma unroll
  for (int i = 0; i < 4; ++i)
#pragma unroll
    for (int j = 0; j < 4; ++j) acc[i][j] = (f32x4){0.f, 0.f, 0.f, 0.f};

  for (int k0 = 0; k0 < K; k0 += 64) {
#pragma unroll
    for (int it = 0; it < 4; ++it) {
      int chunk = it * 256 + tid;       // 0..1023 16B-chunks
      int row = chunk >> 3;
      int kc  = (chunk & 7) << 3;
      async_ld16(&A[(size_t)(m0 + row) * lda + k0 + kc], &As[chunk << 3]);
    }
#pragma unroll
    for (int it = 0; it < 4; ++it) {
      int chunk = it * 256 + tid;
      int row = chunk >> 3;
      int kc  = (chunk & 7) << 3;
      async_ld16(&B[(size_t)(n0 + row) * ldb + k0 + kc], &Bs[chunk << 3]);
    }
    __syncthreads();  // drains vmcnt (global_load_lds) + barrier
#pragma unroll
    for (int kk = 0; kk < 2; ++kk) {
      bf16x8 af[4], bf[4];
#pragma unroll
      for (int i = 0; i < 4; ++i)
        af[i] = *(const bf16x8*)&As[(mw + i * 16 + lr) * 64 + kk * 32 + lq * 8];
#pragma unroll
      for (int j = 0; j < 4; ++j)
        bf[j] = *(const bf16x8*)&Bs[(nw + j * 16 + lr) * 64 + kk * 32 + lq * 8];
#pragma unroll
      for (int i = 0; i < 4; ++i)
#pragma unroll
        for (int j = 0; j < 4; ++j)
          acc[i][j] = __builtin_amdgcn_mfma_f32_16x16x32_bf16(af[i], bf[j], acc[i][j], 0, 0, 0);
    }
    __syncthreads();
  }

#pragma unroll
  for (int j = 0; j < 4; ++j) {
    int n = n0 + nw + j * 16 + lr;
    float bs = 0.f;
    if (bias1) bs += bias1[n];
    if (bias2) bs += bias2[n];
#pragma unroll
    for (int i = 0; i < 4; ++i) {
#pragma unroll
      for (int r = 0; r < 4; ++r) {
        int m = m0 + mw + i * 16 + lq * 4 + r;
        float v = acc[i][j][r] + bs;
        if constexpr (sizeof(OUT_T) == 2)
          C[(size_t)m * ldc + n] = (OUT_T)f2b(v);
        else
          C[(size_t)m * ldc + n] = v;
      }
    }
  }
}

// ---------------------------------------------------------------------------
// 64x64-tile variant for skinny GEMMs (q, ho): 4x the block count of the
// 128-tile kernel on M=2048/N=512 shapes. Same wave layout, 2x2 fragments.
// ---------------------------------------------------------------------------
template <typename OUT_T>
__global__ __launch_bounds__(256) void gemm64(
    const u16* __restrict__ A, int lda,
    const u16* __restrict__ B, int ldb,
    OUT_T* __restrict__ C, int ldc, int K,
    const float* __restrict__ bias1, const float* __restrict__ bias2) {
  __shared__ __align__(16) u16 As[64 * 64];
  __shared__ __align__(16) u16 Bs[64 * 64];

  const int tid  = threadIdx.x;
  int f = blockIdx.y * gridDim.x + blockIdx.x;
  const int nwg = gridDim.x * gridDim.y;
  int g = (nwg & 7) ? f : ((f & 7) * (nwg >> 3) + (f >> 3));
  const int m0 = (g % gridDim.x) * 64;
  const int n0 = (g / gridDim.x) * 64;
  const int wave = tid >> 6, lane = tid & 63;
  const int mw = (wave >> 1) * 32, nw = (wave & 1) * 32;
  const int lr = lane & 15, lq = lane >> 4;

  f32x4 acc[2][2];
#pragma unroll
  for (int i = 0; i < 2; ++i)
#pragma unroll
    for (int j = 0; j < 2; ++j) acc[i][j] = (f32x4){0.f, 0.f, 0.f, 0.f};

  for (int k0 = 0; k0 < K; k0 += 64) {
#pragma unroll
    for (int it = 0; it < 2; ++it) {
      int chunk = it * 256 + tid;       // 0..511 16B-chunks
      int row = chunk >> 3;
      int kc  = (chunk & 7) << 3;
      async_ld16(&A[(size_t)(m0 + row) * lda + k0 + kc], &As[chunk << 3]);
    }
#pragma unroll
    for (int it = 0; it < 2; ++it) {
      int chunk = it * 256 + tid;
      int row = chunk >> 3;
      int kc  = (chunk & 7) << 3;
      async_ld16(&B[(size_t)(n0 + row) * ldb + k0 + kc], &Bs[chunk << 3]);
    }
    __syncthreads();
#pragma unroll
    for (int kk = 0; kk < 2; ++kk) {
      bf16x8 af[2], bf[2];
#pragma unroll
      for (int i = 0; i < 2; ++i)
        af[i] = *(const bf16x8*)&As[(mw + i * 16 + lr) * 64 + kk * 32 + lq * 8];
#pragma unroll
      for (int j = 0; j < 2; ++j)
        bf[j] = *(const bf16x8*)&Bs[(nw + j * 16 + lr) * 64 + kk * 32 + lq * 8];
#pragma unroll
      for (int i = 0; i < 2; ++i)
#pragma unroll
        for (int j = 0; j < 2; ++j)
          acc[i][j] = __builtin_amdgcn_mfma_f32_16x16x32_bf16(af[i], bf[j], acc[i][j], 0, 0, 0);
    }
    __syncthreads();
  }

#pragma unroll
  for (int j = 0; j < 2; ++j) {
    int n = n0 + nw + j * 16 + lr;
    float bs = 0.f;
    if (bias1) bs += bias1[n];
    if (bias2) bs += bias2[n];
#pragma unroll
    for (int i = 0; i < 2; ++i) {
#pragma unroll
      for (int r = 0; r < 4; ++r) {
        int m = m0 + mw + i * 16 + lq * 4 + r;
        float v = acc[i][j][r] + bs;
        if constexpr (sizeof(OUT_T) == 2)
          C[(size_t)m * ldc + n] = (OUT_T)f2b(v);
        else
          C[(size_t)m * ldc + n] = v;
      }
    }
  }
}

// ---------------------------------------------------------------------------
// Embedding gather + f32->bf16: emb[bt][e] = bf16(table[tok[bt]][e]).
// ---------------------------------------------------------------------------
__global__ __launch_bounds__(256) void k_embed(const int* __restrict__ toks,
                                               const float* __restrict__ table,
                                               u16* __restrict__ emb) {
  int id  = blockIdx.x * 256 + threadIdx.x;
  int row = id >> 6;
  int c4  = (id & 63) << 2;
  int tok = toks[row];
  float4 v = *(const float4*)&table[(size_t)tok * E_ + c4];
  ushort4 o;
  o.x = f2b(v.x); o.y = f2b(v.y); o.z = f2b(v.z); o.w = f2b(v.w);
  *(ushort4*)&emb[(size_t)row * E_ + c4] = o;
}

// ---------------------------------------------------------------------------
// Wa transpose + convert: WaT[e][h] = bf16(Wa[h][e])  (512x512).
// ---------------------------------------------------------------------------
__global__ __launch_bounds__(256) void k_transpose(const float* __restrict__ Wa,
                                                   u16* __restrict__ WaT) {
  __shared__ float tle[32][33];
  int bx = blockIdx.x * 32;  // h
  int by = blockIdx.y * 32;  // e
  int tid = threadIdx.x;
  for (int i = tid; i < 1024; i += 256) {
    int r = i >> 5, c = i & 31;
    tle[r][c] = Wa[(size_t)(bx + r) * ENC_ + by + c];
  }
  __syncthreads();
  for (int i = tid; i < 1024; i += 256) {
    int r = i >> 5, c = i & 31;
    WaT[(size_t)(by + r) * H_ + bx + c] = f2b(tle[c][r]);
  }
}

// ---------------------------------------------------------------------------
// Sequential LSTM core. 64 persistent blocks. Block n owns h-indices
// [8n,8n+8) => W_hh rows {g*512+8n+j} held in regs.
//
// Round 7 = round-3 structure (proven 278us) with two local tweaks:
//  - poll uses u64 loads in the tid-contiguous coalescing layout (half the
//    request count of u32), with PER-U32-HALF sentinel check (a u64 spans
//    two producer threads' stores; u64==~0 would accept half-stale words).
//  - s_sleep(1) backoff only on retry (reduces re-poll congestion, cannot
//    delay first observation).
// Exchange: sentinel data-is-flag. Hbuf slots 1..64 pre-poisoned 0xFF
// (0xFFFFFFFF = two bf16 NaNs, impossible from f2b(sigm*tanh)). Writers
// issue packed-u32 relaxed-AGENT stores; readers poll the data itself via
// relaxed-AGENT loads (bypass stale per-XCD L2), then restage to LDS.
// ---------------------------------------------------------------------------
__global__ __launch_bounds__(256) void k_lstm(
    const u16* __restrict__ Whh,   // bf16 [2048][512]
    const float* __restrict__ gp,  // gates_pre [B*T][2048]
    const float* __restrict__ c0,  // [32][512] f32
    u16* __restrict__ Hbuf,        // [65][32][512] bf16; slots 1..64 poisoned
    u16* __restrict__ hc) {        // [B*T][1024] bf16, cols 0..511 = h
  const int blk  = blockIdx.x;
  const int tid  = threadIdx.x;
  const int wave = tid >> 6, lane = tid & 63;
  const int mi = wave >> 1, ni = wave & 1;
  const int lr = lane & 15, lq = lane >> 4;

  // B-operand (W_hh rows) resident in registers for whole kernel.
  const int p    = ni * 16 + lr;                          // col within 32-set
  const int grow = (p >> 3) * H_ + blk * 8 + (p & 7);     // global gate row
  bf16x8 bfr[16];
#pragma unroll
  for (int ks = 0; ks < 16; ++ks)
    bfr[ks] = *(const bf16x8*)&Whh[(size_t)grow * H_ + ks * 32 + lq * 8];

  // c-state: thread (b=tid>>3, j=tid&7) owns c[b][blk*8+j] in a register.
  const int pb = tid >> 3, pj = tid & 7;
  const int hidx = blk * 8 + pj;
  float c = c0[pb * H_ + hidx];

  __shared__ __align__(16) u16 Hs[32 * 512];  // 32KB: h_{t-1}, all 32 batches
  __shared__ float G[32][33];                 // +1 pad

  const int am = mi * 16 + lr;

  // prefetch gp for t=0
  float gpr[4];
#pragma unroll
  for (int r = 0; r < 4; ++r)
    gpr[r] = gp[(size_t)((mi * 16 + lq * 4 + r) * T_ + 0) * 2048 + grow];

  // stage h0 (Hbuf slot 0) into LDS (written by a prior kernel: coherent)
#pragma unroll
  for (int it = 0; it < 8; ++it) {
    int chunk = it * 256 + tid;  // 0..2047 16B-chunks
    async_ld16(&Hbuf[chunk * 8], &Hs[chunk * 8]);
  }
  __syncthreads();

  for (int t = 0; t < T_; ++t) {
    f32x4 acc = (f32x4){0.f, 0.f, 0.f, 0.f};
#pragma unroll
    for (int ks = 0; ks < 16; ++ks) {
      bf16x8 a = *(const bf16x8*)&Hs[am * H_ + ks * 32 + lq * 8];
      acc = __builtin_amdgcn_mfma_f32_16x16x32_bf16(a, bfr[ks], acc, 0, 0, 0);
    }
#pragma unroll
    for (int r = 0; r < 4; ++r)
      G[mi * 16 + lq * 4 + r][p] = acc[r] + gpr[r];
    __syncthreads();  // G visible; also: all Hs reads for step t are done
    // pointwise: i,f,g,o at cols j, 8+j, 16+j, 24+j of the 32-set
    float gi = G[pb][pj], gf = G[pb][8 + pj], gg = G[pb][16 + pj], go = G[pb][24 + pj];
    c = sigm(gf) * c + sigm(gi) * tanhf(gg);
    float h = sigm(go) * tanhf(c);
    u16 hb = f2b(h);
    // pack neighbor's h (pj^1, same wave) and publish as one u32.
    u32 other = (u32)__shfl_xor((int)(u32)hb, 1);
    if (!(tid & 1)) {
      u32 pk = (u32)hb | (other << 16);
      __hip_atomic_store((u32*)&Hbuf[(size_t)(t + 1) * (B_ * H_) + pb * H_ + hidx], pk,
                         __ATOMIC_RELAXED, __HIP_MEMORY_SCOPE_AGENT);
      *(u32*)&hc[(size_t)(pb * T_ + t) * 1024 + hidx] = pk;
    }

    if (t < T_ - 1) {
      // prefetch next step's gp: HBM latency overlaps the data-poll
#pragma unroll
      for (int r = 0; r < 4; ++r)
        gpr[r] = gp[(size_t)((mi * 16 + lq * 4 + r) * T_ + t + 1) * 2048 + grow];
      // poll-read h_t: data is its own readiness flag (u64, tid-contiguous)
      const u64* h8 = (const u64*)&Hbuf[(size_t)(t + 1) * (B_ * H_)];
      u64 tmp[16];
#pragma unroll
      for (int it = 0; it < 16; ++it)
        tmp[it] = __hip_atomic_load(&h8[it * 256 + tid], __ATOMIC_RELAXED,
                                    __HIP_MEMORY_SCOPE_AGENT);
      for (;;) {
        u32 bad = 0;
#pragma unroll
        for (int it = 0; it < 16; ++it) {
          u32 lo = (u32)tmp[it], hi = (u32)(tmp[it] >> 32);
          bad |= (lo == 0xFFFFFFFFu) | (hi == 0xFFFFFFFFu);
        }
        if (!bad) break;
        __builtin_amdgcn_s_sleep(1);
#pragma unroll
        for (int it = 0; it < 16; ++it) {
          u32 lo = (u32)tmp[it], hi = (u32)(tmp[it] >> 32);
          if (lo == 0xFFFFFFFFu || hi == 0xFFFFFFFFu)
            tmp[it] = __hip_atomic_load(&h8[it * 256 + tid], __ATOMIC_RELAXED,
                                        __HIP_MEMORY_SCOPE_AGENT);
        }
      }
#pragma unroll
      for (int it = 0; it < 16; ++it)
        *(u64*)&Hs[(size_t)(it * 256 + tid) * 4] = tmp[it];
      __syncthreads();
    }
  }
}

// ---------------------------------------------------------------------------
// Attention: one block per (b,t). scores = q . enc, mask, softmax, ctx.
// enc here is the bf16 copy. Writes ctx (bf16) into hc cols 512..1023.
// ---------------------------------------------------------------------------
__global__ __launch_bounds__(256) void k_attn(
    const u16* __restrict__ q,    // bf16 [B*T][512]
    const u16* __restrict__ enc,  // bf16 [B][S][512]
    const int* __restrict__ lens, // [B]
    u16* __restrict__ hc) {       // bf16 [B*T][1024]
  const int bt = blockIdx.x;
  const int b  = bt >> 6;  // bt = b*T + t
  const int tid = threadIdx.x;
  const int len = lens[b];

  __shared__ float qs[512];
  __shared__ float sc[128];
  __shared__ float red2[256];
  __shared__ float sred[2];

  for (int i = tid; i < 512; i += 256) qs[i] = b2f(q[(size_t)bt * 512 + i]);
  __syncthreads();

  // scores: thread (s = tid&127, half = tid>>7) sums 256 of 512 k's
  {
    int s = tid & 127, half = tid >> 7;
    const u16* er = &enc[((size_t)b * S_ + s) * 512 + half * 256];
    const float* qb = &qs[half * 256];
    float a = 0.f;
#pragma unroll 4
    for (int k = 0; k < 256; k += 8) {
      uint4 raw = *(const uint4*)&er[k];
      u32 w0 = raw.x, w1 = raw.y, w2 = raw.z, w3 = raw.w;
      union { u32 i; float f; } lo, hi;
      lo.i = w0 << 16;          a += lo.f * qb[k + 0];
      hi.i = w0 & 0xffff0000u;  a += hi.f * qb[k + 1];
      lo.i = w1 << 16;          a += lo.f * qb[k + 2];
      hi.i = w1 & 0xffff0000u;  a += hi.f * qb[k + 3];
      lo.i = w2 << 16;          a += lo.f * qb[k + 4];
      hi.i = w2 & 0xffff0000u;  a += hi.f * qb[k + 5];
      lo.i = w3 << 16;          a += lo.f * qb[k + 6];
      hi.i = w3 & 0xffff0000u;  a += hi.f * qb[k + 7];
    }
    red2[tid] = a;
  }
  __syncthreads();
  if (tid < 128) {
    float v = red2[tid] + red2[tid + 128];
    sc[tid] = (tid < len) ? v : -1e30f;
  }
  __syncthreads();
  if (tid < 64) {
    float m = fmaxf(sc[tid], sc[tid + 64]);
#pragma unroll
    for (int o = 32; o > 0; o >>= 1) m = fmaxf(m, __shfl_down(m, o));
    if (tid == 0) sred[0] = m;
  }
  __syncthreads();
  float mx = sred[0];
  if (tid < 128) sc[tid] = __expf(sc[tid] - mx);
  __syncthreads();
  if (tid < 64) {
    float s2 = sc[tid] + sc[tid + 64];
#pragma unroll
    for (int o = 32; o > 0; o >>= 1) s2 += __shfl_down(s2, o);
    if (tid == 0) sred[1] = s2;
  }
  __syncthreads();
  float inv = 1.0f / sred[1];

  // ctx: thread owns e-pair (2*tid, 2*tid+1); one packed u32 load per s
  // (was: two scalar u16 loads per s -- Common-mistake #2).
  float a0 = 0.f, a1 = 0.f;
  const u16* eb = &enc[(size_t)b * S_ * 512 + 2 * tid];
#pragma unroll 4
  for (int s = 0; s < S_; ++s) {
    float at = sc[s];
    u32 w = *(const u32*)&eb[(size_t)s * 512];
    union { u32 i; float f; } lo, hi;
    lo.i = w << 16; hi.i = w & 0xffff0000u;
    a0 += at * lo.f;
    a1 += at * hi.f;
  }
  u32 pk = (u32)f2b(a0 * inv) | ((u32)f2b(a1 * inv) << 16);
  *(u32*)&hc[(size_t)bt * 1024 + 512 + 2 * tid] = pk;
}

// ---------------------------------------------------------------------------
extern "C" void kernel_launch(void* const* d_in, const int* in_sizes, int n_in,
                              void* d_out, int out_size, void* d_ws, size_t ws_size,
                              hipStream_t stream) {
  const int*   toks  = (const int*)d_in[0];
  const float* enc   = (const float*)d_in[1];
  const int*   lens  = (const int*)d_in[2];
  const float* h0    = (const float*)d_in[3];
  const float* c0    = (const float*)d_in[4];
  const float* table = (const float*)d_in[5];
  const float* W_ih  = (const float*)d_in[6];
  const float* W_hh  = (const float*)d_in[7];
  const float* b_ih  = (const float*)d_in[8];
  const float* b_hh  = (const float*)d_in[9];
  const float* Wa    = (const float*)d_in[10];
  const float* Wc_w  = (const float*)d_in[11];
  const float* Wc_b  = (const float*)d_in[12];
  const float* Wo_w  = (const float*)d_in[13];
  const float* Wo_b  = (const float*)d_in[14];
  float* out = (float*)d_out;

  char* ws = (char*)d_ws;
  size_t off = 0;
  auto alloc = [&](size_t bytes) {
    void* pp = ws + off;
    off += (bytes + 255) & ~(size_t)255;
    return pp;
  };
  float* gp    = (float*)alloc((size_t)B_ * T_ * 2048 * 4);    // 16.8 MB
  u16*   emb   = (u16*)alloc((size_t)B_ * T_ * E_ * 2);        // 1 MB
  u16*   Hbuf  = (u16*)alloc((size_t)(T_ + 1) * B_ * H_ * 2);  // 2.1 MB
  u16*   hc    = (u16*)alloc((size_t)B_ * T_ * 1024 * 2);      // 4 MB
  u16*   q     = (u16*)alloc((size_t)B_ * T_ * ENC_ * 2);      // 2 MB
  u16*   WaT   = (u16*)alloc((size_t)ENC_ * H_ * 2);           // 0.5 MB
  u16*   ho    = (u16*)alloc((size_t)B_ * T_ * H_ * 2);        // 2 MB
  u16*   Wihb  = (u16*)alloc((size_t)2048 * E_ * 2);           // 1 MB
  u16*   Whhb  = (u16*)alloc((size_t)2048 * H_ * 2);           // 2 MB
  u16*   Wcwb  = (u16*)alloc((size_t)H_ * 1024 * 2);           // 1 MB
  u16*   Wowb  = (u16*)alloc((size_t)V_ * H_ * 2);             // 32.8 MB
  u16*   encb  = (u16*)alloc((size_t)B_ * S_ * ENC_ * 2);      // 4.2 MB
  (void)in_sizes; (void)n_in; (void)out_size; (void)ws_size;

  // poison Hbuf slots 1..64 with the sentinel (0xFF bytes -> 0xFFFFFFFF words)
  hipMemsetAsync(Hbuf + (size_t)B_ * H_, 0xFF, (size_t)T_ * B_ * H_ * 2, stream);

  // 0. all f32 -> bf16 converts in ONE launch
  CvtJobs j;
  int e0 = 2048 * E_ / 4;            // W_ih
  int e1 = e0 + 2048 * H_ / 4;       // W_hh
  int e2 = e1 + H_ * 1024 / 4;       // Wc_w
  int e3 = e2 + V_ * H_ / 4;         // Wo_w
  int e4 = e3 + B_ * S_ * ENC_ / 4;  // enc
  int e5 = e4 + B_ * H_ / 4;         // h0 -> Hbuf slot 0
  j.src[0] = W_ih; j.dst[0] = Wihb; j.end[0] = e0;
  j.src[1] = W_hh; j.dst[1] = Whhb; j.end[1] = e1;
  j.src[2] = Wc_w; j.dst[2] = Wcwb; j.end[2] = e2;
  j.src[3] = Wo_w; j.dst[3] = Wowb; j.end[3] = e3;
  j.src[4] = enc;  j.dst[4] = encb; j.end[4] = e4;
  j.src[5] = h0;   j.dst[5] = Hbuf; j.end[5] = e5;
  k_cvt_all<<<(e5 + 255) / 256, 256, 0, stream>>>(j);
  // 1. embedding gather (+convert)
  k_embed<<<512, 256, 0, stream>>>(toks, table, emb);
  // 2. gates_pre = emb @ W_ih^T + b_ih + b_hh   [2048 x 2048], K=256, f32 out
  gemm_bt<float><<<dim3(16, 16), 256, 0, stream>>>(emb, E_, Wihb, E_, gp, 2048, E_, b_ih, b_hh);
  // 3. WaT = Wa^T (bf16)
  k_transpose<<<dim3(16, 16), 256, 0, stream>>>(Wa, WaT);
  // 4. sequential LSTM core -> h into hc[:, 0:512] and Hbuf slots 1..64
  k_lstm<<<64, 256, 0, stream>>>(Whhb, gp, c0, Hbuf, hc);
  // 5. q = h @ Wa  == hc[:,0:512] @ WaT^T   [2048 x 512], K=512, bf16 out
  gemm64<u16><<<dim3(32, 8), 256, 0, stream>>>(hc, 1024, WaT, H_, q, ENC_, H_, nullptr, nullptr);
  // 6. attention -> ctx into hc[:, 512:1024]
  k_attn<<<B_ * T_, 256, 0, stream>>>(q, encb, lens, hc);
  // 7. ho = [h,ctx] @ Wc_w^T + Wc_b   [2048 x 512], K=1024
  gemm64<u16><<<dim3(32, 8), 256, 0, stream>>>(hc, 1024, Wcwb, 1024, ho, H_, 1024, Wc_b, nullptr);
  // 8. logits = ho @ Wo^T + Wo_b -> d_out (f32)   [2048 x 32000], K=512
  gemm_bt<float><<<dim3(16, 250), 256, 0, stream>>>(ho, H_, Wowb, H_, out, V_, H_, Wo_b, nullptr);
}